// Round 1
// baseline (469.696 us; speedup 1.0000x reference)
//
#include <hip/hip_runtime.h>

// VectorQuantiser on MI355X.
// Inputs:  d_in[0] = z_e fp32 (16*2048*256 = 8388608), d_in[1] = codebook fp32 (1024*256)
// Outputs (flat fp32, concatenated): z_q [8388608] | similarity [33554432] | ids [32768] | loss [1]
//
// Pipeline:
//   A prep:     z_e,codebook -> bf16 copies (z bf16 parked in the z_q slot of d_out,
//               overwritten by C later); row norms nsz/nse + sqrt + rsqrt in ws.
//   B gemm_sim: bf16 MFMA 128x128 tile GEMM, fused epilogue writes similarity (fp32).
//   C select:   per row (1 wave): rebuild bf16-dist from stored sim, find min + all
//               candidates within margin 1.0, fp32-exact rescore of candidates ->
//               exact argmin w/ low-index tie-break; write ids (as float), gather z_q,
//               atomic loss partial.
//   D finalize: loss_vq = (1+0.25) * sum/32768.

#define M_ROWS 32768
#define KCODES 1024
#define DDIM   256

typedef __bf16 bf16_t;
typedef __attribute__((ext_vector_type(8))) bf16_t bf16x8;
typedef __attribute__((ext_vector_type(4))) float f32x4;

__device__ __forceinline__ unsigned short f2bf(float f) {
  unsigned u = __float_as_uint(f);
  u += 0x7FFFu + ((u >> 16) & 1u);   // round-to-nearest-even
  return (unsigned short)(u >> 16);
}

__device__ __forceinline__ float wave_sum(float p) {
#pragma unroll
  for (int o = 1; o < 64; o <<= 1) p += __shfl_xor(p, o);
  return p;
}
__device__ __forceinline__ float wave_min(float p) {
#pragma unroll
  for (int o = 1; o < 64; o <<= 1) p = fminf(p, __shfl_xor(p, o));
  return p;
}

// ---------------- Kernel A: convert + norms ----------------
__global__ __launch_bounds__(256) void prep_kernel(
    const float* __restrict__ ze, const float* __restrict__ cb,
    unsigned short* __restrict__ zb, unsigned short* __restrict__ cbb,
    float* __restrict__ sqz, float* __restrict__ rsqz,
    float* __restrict__ nse, float* __restrict__ sqe, float* __restrict__ rsqe,
    float* __restrict__ loss_acc)
{
  const int t = threadIdx.x;
  if (blockIdx.x == 0 && t == 0) *loss_acc = 0.0f;   // zero accumulator every launch
  const int lane = t & 63;
  const int row = blockIdx.x * 4 + (t >> 6);         // wave per row; rows 0..33791
  if (row < M_ROWS) {
    const float4 z = ((const float4*)ze)[(size_t)row * 64 + lane];
    ushort4 u;
    u.x = f2bf(z.x); u.y = f2bf(z.y); u.z = f2bf(z.z); u.w = f2bf(z.w);
    ((ushort4*)zb)[(size_t)row * 64 + lane] = u;
    float p = wave_sum(z.x*z.x + z.y*z.y + z.z*z.z + z.w*z.w);
    if (lane == 0) { float s = sqrtf(p); sqz[row] = s; rsqz[row] = 1.0f / s; }
  } else {
    const int r = row - M_ROWS;                      // 0..1023
    const float4 e = ((const float4*)cb)[(size_t)r * 64 + lane];
    ushort4 u;
    u.x = f2bf(e.x); u.y = f2bf(e.y); u.z = f2bf(e.z); u.w = f2bf(e.w);
    ((ushort4*)cbb)[(size_t)r * 64 + lane] = u;
    float p = wave_sum(e.x*e.x + e.y*e.y + e.z*e.z + e.w*e.w);
    if (lane == 0) { nse[r] = p; float s = sqrtf(p); sqe[r] = s; rsqe[r] = 1.0f / s; }
  }
}

// ---------------- Kernel B: bf16 MFMA GEMM + similarity epilogue ----------------
// Tile 128(M) x 128(N) x 64(K-step), 4 waves (2x2 of 64x64), 16x16x32 bf16 MFMA.
// LDS XOR-swizzle: logical (row, quad q of 16B) stored at phys quad q ^ (row&7).
// global_load_lds writes linearly (base + lane*16B) -> pre-swizzle the GLOBAL src.
__global__ __launch_bounds__(256, 2) void gemm_sim_kernel(
    const unsigned short* __restrict__ zb, const unsigned short* __restrict__ cbb,
    const float* __restrict__ rsqz, const float* __restrict__ rsqe,
    float* __restrict__ sim)
{
  __shared__ __attribute__((aligned(128))) unsigned short lds[16384]; // A [0,8192), B [8192,16384)
  const int tid  = threadIdx.x;
  const int wv   = tid >> 6, lane = tid & 63;
  const int bid  = blockIdx.x;
  // XCD swizzle (nwg=2048, divisible by 8 -> simple bijective form)
  const int swz  = (bid & 7) * 256 + (bid >> 3);
  const long row0 = (long)(swz >> 3) * 128;   // 256 row tiles
  const int  col0 = (swz & 7) * 128;          // 8 code tiles

  f32x4 acc[4][4] = {};

  const int rr = lane >> 3, qq = lane & 7;
  const int sq = ((qq ^ rr) << 3);            // pre-swizzled source quad (8 bf16 = 16B)

  for (int kt = 0; kt < 4; ++kt) {
    const int k0 = kt * 64;
#pragma unroll
    for (int i = 0; i < 4; ++i) {
      const int rbase = wv * 32 + i * 8;      // multiple of 8 -> (row&7)==rr
      const unsigned short* srca = zb  + ((size_t)(row0 + rbase + rr)) * DDIM + k0 + sq;
      const unsigned short* srcb = cbb + ((size_t)(col0 + rbase + rr)) * DDIM + k0 + sq;
      __builtin_amdgcn_global_load_lds((const __attribute__((address_space(1))) void*)srca,
                                       (__attribute__((address_space(3))) void*)&lds[rbase * 64],
                                       16, 0, 0);
      __builtin_amdgcn_global_load_lds((const __attribute__((address_space(1))) void*)srcb,
                                       (__attribute__((address_space(3))) void*)&lds[8192 + rbase * 64],
                                       16, 0, 0);
    }
    __syncthreads();
    const int r16 = lane & 15, g = lane >> 4;
#pragma unroll
    for (int ks = 0; ks < 2; ++ks) {
      bf16x8 af[4], bfr[4];
#pragma unroll
      for (int mi = 0; mi < 4; ++mi) {
        const int r  = (wv >> 1) * 64 + mi * 16 + r16;
        const int qy = ((ks * 4 + g) ^ (r & 7)) << 4;
        af[mi] = *(const bf16x8*)((const char*)lds + r * 128 + qy);
      }
#pragma unroll
      for (int ni = 0; ni < 4; ++ni) {
        const int r  = (wv & 1) * 64 + ni * 16 + r16;
        const int qy = ((ks * 4 + g) ^ (r & 7)) << 4;
        bfr[ni] = *(const bf16x8*)((const char*)lds + 16384 + r * 128 + qy);
      }
#pragma unroll
      for (int mi = 0; mi < 4; ++mi)
#pragma unroll
        for (int ni = 0; ni < 4; ++ni)
          acc[mi][ni] = __builtin_amdgcn_mfma_f32_16x16x32_bf16(af[mi], bfr[ni], acc[mi][ni], 0, 0, 0);
    }
    __syncthreads();
  }

  // Epilogue: sim = dot * rsqz[row] * rsqe[col].  C/D layout: col = lane&15, row = (lane>>4)*4 + j.
  const int r16 = lane & 15, g = lane >> 4;
  const int wm = wv >> 1, wn = wv & 1;
#pragma unroll
  for (int mi = 0; mi < 4; ++mi) {
#pragma unroll
    for (int j = 0; j < 4; ++j) {
      const long row = row0 + wm * 64 + mi * 16 + g * 4 + j;
      const float rz = rsqz[row];
      float* so = sim + (size_t)row * KCODES + col0 + wn * 64 + r16;
#pragma unroll
      for (int ni = 0; ni < 4; ++ni)
        so[ni * 16] = acc[mi][ni][j] * rz * rsqe[col0 + wn * 64 + ni * 16 + r16];
    }
  }
}

// ---------------- Kernel C: argmin (exact fp32 rescore) + z_q + loss ----------------
__global__ __launch_bounds__(256) void select_kernel(
    const float* __restrict__ ze, const float* __restrict__ cb,
    const float* __restrict__ sim, const float* __restrict__ sqz,
    const float* __restrict__ nse, const float* __restrict__ sqe,
    float* __restrict__ zq, float* __restrict__ ids, float* __restrict__ loss_acc)
{
  __shared__ float s_nse[KCODES];
  __shared__ float s_sqe[KCODES];
  const int t = threadIdx.x;
  ((float4*)s_nse)[t] = ((const float4*)nse)[t];
  ((float4*)s_sqe)[t] = ((const float4*)sqe)[t];
  __syncthreads();

  const int lane = t & 63;
  const int row  = blockIdx.x * 4 + (t >> 6);        // wave per row
  const float4 zr = ((const float4*)ze)[(size_t)row * 64 + lane];
  const float  c2 = 2.0f * sqz[row];
  const float4* simr = (const float4*)(sim + (size_t)row * KCODES);

  // dist(row,k) - nsz  (nsz is per-row constant: irrelevant for argmin)
  float v[16];
  float vmin = INFINITY;
#pragma unroll
  for (int i = 0; i < 4; ++i) {
    const float4 s4 = simr[i * 64 + lane];
    const float sv[4] = {s4.x, s4.y, s4.z, s4.w};
#pragma unroll
    for (int c = 0; c < 4; ++c) {
      const int k = i * 256 + lane * 4 + c;
      const float val = s_nse[k] - c2 * s_sqe[k] * sv[c];
      v[i * 4 + c] = val;
      vmin = fminf(vmin, val);
    }
  }
  vmin = wave_min(vmin);
  const float lim = vmin + 1.0f;   // margin ~19 sigma of bf16-dot error

  float tbest = INFINITY; int kbest = KCODES;
#pragma unroll
  for (int idx = 0; idx < 16; ++idx) {
    unsigned long long m = __ballot(v[idx] <= lim);
    const int i = idx >> 2, c = idx & 3;
    while (m) {                                      // uniform across wave
      const int lb = __ffsll(m) - 1;
      m &= m - 1;
      const int kc = i * 256 + lb * 4 + c;
      const float4 er = ((const float4*)cb)[(size_t)kc * 64 + lane];
      float p = wave_sum(zr.x*er.x + zr.y*er.y + zr.z*er.z + zr.w*er.w);
      const float tv = s_nse[kc] - 2.0f * p;         // exact-fp32 dist - nsz
      if (tv < tbest || (tv == tbest && kc < kbest)) { tbest = tv; kbest = kc; }
    }
  }

  const float4 er = ((const float4*)cb)[(size_t)kbest * 64 + lane];
  ((float4*)zq)[(size_t)row * 64 + lane] = er;
  const float dx = zr.x - er.x, dy = zr.y - er.y, dz = zr.z - er.z, dw = zr.w - er.w;
  const float ss = wave_sum(dx*dx + dy*dy + dz*dz + dw*dw);
  if (lane == 0) {
    ids[row] = (float)kbest;
    atomicAdd(loss_acc, sqrtf(ss));
  }
}

// ---------------- Kernel D: finalize loss ----------------
__global__ void finalize_kernel(const float* __restrict__ loss_acc, float* __restrict__ out_loss) {
  if (threadIdx.x == 0) out_loss[0] = 1.25f * loss_acc[0] / 32768.0f;
}

extern "C" void kernel_launch(void* const* d_in, const int* in_sizes, int n_in,
                              void* d_out, int out_size, void* d_ws, size_t ws_size,
                              hipStream_t stream) {
  const float* ze = (const float*)d_in[0];
  const float* cb = (const float*)d_in[1];

  float* out  = (float*)d_out;
  float* zq   = out;                    // 8388608
  float* sim  = out + 8388608;          // 33554432
  float* ids  = out + 41943040;         // 32768
  float* lout = out + 41975808;         // 1

  char* w = (char*)d_ws;                // ~780 KB of ws used
  unsigned short* cbb = (unsigned short*)w;           // 1024*256 bf16 = 512 KB
  float* sqz  = (float*)(w + 524288);   // 32768 f32
  float* rsqz = (float*)(w + 655360);   // 32768 f32
  float* nse  = (float*)(w + 786432);   // 1024 f32
  float* sqe  = (float*)(w + 790528);   // 1024 f32
  float* rsqe = (float*)(w + 794624);   // 1024 f32
  float* lacc = (float*)(w + 798720);   // 1 f32

  // bf16 z_e parked in the z_q output slot (16.8 MB < 33.5 MB); select_kernel
  // never reads it and overwrites the slot with the real z_q afterwards.
  unsigned short* zb = (unsigned short*)d_out;

  prep_kernel<<<8448, 256, 0, stream>>>(ze, cb, zb, cbb, sqz, rsqz, nse, sqe, rsqe, lacc);
  gemm_sim_kernel<<<2048, 256, 0, stream>>>(zb, cbb, rsqz, rsqe, sim);
  select_kernel<<<8192, 256, 0, stream>>>(ze, cb, sim, sqz, nse, sqe, zq, ids, lacc);
  finalize_kernel<<<1, 64, 0, stream>>>(lacc, lout);
}

// Round 2
// 78.303 us; speedup vs baseline: 5.9984x; 5.9984x over previous
//
#include <hip/hip_runtime.h>

// VectorQuantiser on MI355X.
// Inputs:  d_in[0] = z_e fp32 (16*2048*256 = 8388608), d_in[1] = codebook fp32 (1024*256)
// Outputs (flat fp32, concatenated): z_q [8388608] | similarity [33554432] | ids [32768] | loss [1]
//
// Pipeline:
//   A prep:     z_e,codebook -> bf16 copies (z bf16 parked in the z_q slot of d_out,
//               overwritten by C later); row norms nsz/nse + sqrt + rsqrt in ws.
//   B gemm_sim: bf16 MFMA 128x128 tile GEMM, fused epilogue writes similarity (fp32).
//   C select:   per row (1 wave): rebuild bf16-dist from stored sim, find min + all
//               candidates within margin 1.0, fp32-exact rescore of candidates ->
//               exact argmin w/ low-index tie-break; write ids (as float), gather z_q,
//               per-BLOCK loss partial (no atomics -- same-address atomicAdd was 426us
//               of serialization in round 1).
//   D finalize: deterministic tree-sum of 8192 partials; loss = 1.25 * sum / 32768.

#define M_ROWS 32768
#define KCODES 1024
#define DDIM   256

typedef __bf16 bf16_t;
typedef __attribute__((ext_vector_type(8))) bf16_t bf16x8;
typedef __attribute__((ext_vector_type(4))) float f32x4;

__device__ __forceinline__ unsigned short f2bf(float f) {
  unsigned u = __float_as_uint(f);
  u += 0x7FFFu + ((u >> 16) & 1u);   // round-to-nearest-even
  return (unsigned short)(u >> 16);
}

__device__ __forceinline__ float wave_sum(float p) {
#pragma unroll
  for (int o = 1; o < 64; o <<= 1) p += __shfl_xor(p, o);
  return p;
}
__device__ __forceinline__ float wave_min(float p) {
#pragma unroll
  for (int o = 1; o < 64; o <<= 1) p = fminf(p, __shfl_xor(p, o));
  return p;
}

// ---------------- Kernel A: convert + norms ----------------
__global__ __launch_bounds__(256) void prep_kernel(
    const float* __restrict__ ze, const float* __restrict__ cb,
    unsigned short* __restrict__ zb, unsigned short* __restrict__ cbb,
    float* __restrict__ sqz, float* __restrict__ rsqz,
    float* __restrict__ nse, float* __restrict__ sqe, float* __restrict__ rsqe)
{
  const int t = threadIdx.x;
  const int lane = t & 63;
  const int row = blockIdx.x * 4 + (t >> 6);         // wave per row; rows 0..33791
  if (row < M_ROWS) {
    const float4 z = ((const float4*)ze)[(size_t)row * 64 + lane];
    ushort4 u;
    u.x = f2bf(z.x); u.y = f2bf(z.y); u.z = f2bf(z.z); u.w = f2bf(z.w);
    ((ushort4*)zb)[(size_t)row * 64 + lane] = u;
    float p = wave_sum(z.x*z.x + z.y*z.y + z.z*z.z + z.w*z.w);
    if (lane == 0) { float s = sqrtf(p); sqz[row] = s; rsqz[row] = 1.0f / s; }
  } else {
    const int r = row - M_ROWS;                      // 0..1023
    const float4 e = ((const float4*)cb)[(size_t)r * 64 + lane];
    ushort4 u;
    u.x = f2bf(e.x); u.y = f2bf(e.y); u.z = f2bf(e.z); u.w = f2bf(e.w);
    ((ushort4*)cbb)[(size_t)r * 64 + lane] = u;
    float p = wave_sum(e.x*e.x + e.y*e.y + e.z*e.z + e.w*e.w);
    if (lane == 0) { nse[r] = p; float s = sqrtf(p); sqe[r] = s; rsqe[r] = 1.0f / s; }
  }
}

// ---------------- Kernel B: bf16 MFMA GEMM + similarity epilogue ----------------
// Tile 128(M) x 128(N) x 64(K-step), 4 waves (2x2 of 64x64), 16x16x32 bf16 MFMA.
// LDS XOR-swizzle: logical (row, quad q of 16B) stored at phys quad q ^ (row&7).
// global_load_lds writes linearly (base + lane*16B) -> pre-swizzle the GLOBAL src.
__global__ __launch_bounds__(256, 2) void gemm_sim_kernel(
    const unsigned short* __restrict__ zb, const unsigned short* __restrict__ cbb,
    const float* __restrict__ rsqz, const float* __restrict__ rsqe,
    float* __restrict__ sim)
{
  __shared__ __attribute__((aligned(128))) unsigned short lds[16384]; // A [0,8192), B [8192,16384)
  const int tid  = threadIdx.x;
  const int wv   = tid >> 6, lane = tid & 63;
  const int bid  = blockIdx.x;
  // XCD swizzle (nwg=2048, divisible by 8 -> simple bijective form)
  const int swz  = (bid & 7) * 256 + (bid >> 3);
  const long row0 = (long)(swz >> 3) * 128;   // 256 row tiles
  const int  col0 = (swz & 7) * 128;          // 8 code tiles

  f32x4 acc[4][4] = {};

  const int rr = lane >> 3, qq = lane & 7;
  const int sq = ((qq ^ rr) << 3);            // pre-swizzled source quad (8 bf16 = 16B)

  for (int kt = 0; kt < 4; ++kt) {
    const int k0 = kt * 64;
#pragma unroll
    for (int i = 0; i < 4; ++i) {
      const int rbase = wv * 32 + i * 8;      // multiple of 8 -> (row&7)==rr
      const unsigned short* srca = zb  + ((size_t)(row0 + rbase + rr)) * DDIM + k0 + sq;
      const unsigned short* srcb = cbb + ((size_t)(col0 + rbase + rr)) * DDIM + k0 + sq;
      __builtin_amdgcn_global_load_lds((const __attribute__((address_space(1))) void*)srca,
                                       (__attribute__((address_space(3))) void*)&lds[rbase * 64],
                                       16, 0, 0);
      __builtin_amdgcn_global_load_lds((const __attribute__((address_space(1))) void*)srcb,
                                       (__attribute__((address_space(3))) void*)&lds[8192 + rbase * 64],
                                       16, 0, 0);
    }
    __syncthreads();
    const int r16 = lane & 15, g = lane >> 4;
#pragma unroll
    for (int ks = 0; ks < 2; ++ks) {
      bf16x8 af[4], bfr[4];
#pragma unroll
      for (int mi = 0; mi < 4; ++mi) {
        const int r  = (wv >> 1) * 64 + mi * 16 + r16;
        const int qy = ((ks * 4 + g) ^ (r & 7)) << 4;
        af[mi] = *(const bf16x8*)((const char*)lds + r * 128 + qy);
      }
#pragma unroll
      for (int ni = 0; ni < 4; ++ni) {
        const int r  = (wv & 1) * 64 + ni * 16 + r16;
        const int qy = ((ks * 4 + g) ^ (r & 7)) << 4;
        bfr[ni] = *(const bf16x8*)((const char*)lds + 16384 + r * 128 + qy);
      }
#pragma unroll
      for (int mi = 0; mi < 4; ++mi)
#pragma unroll
        for (int ni = 0; ni < 4; ++ni)
          acc[mi][ni] = __builtin_amdgcn_mfma_f32_16x16x32_bf16(af[mi], bfr[ni], acc[mi][ni], 0, 0, 0);
    }
    __syncthreads();
  }

  // Epilogue: sim = dot * rsqz[row] * rsqe[col].  C/D layout: col = lane&15, row = (lane>>4)*4 + j.
  const int r16 = lane & 15, g = lane >> 4;
  const int wm = wv >> 1, wn = wv & 1;
#pragma unroll
  for (int mi = 0; mi < 4; ++mi) {
#pragma unroll
    for (int j = 0; j < 4; ++j) {
      const long row = row0 + wm * 64 + mi * 16 + g * 4 + j;
      const float rz = rsqz[row];
      float* so = sim + (size_t)row * KCODES + col0 + wn * 64 + r16;
#pragma unroll
      for (int ni = 0; ni < 4; ++ni)
        so[ni * 16] = acc[mi][ni][j] * rz * rsqe[col0 + wn * 64 + ni * 16 + r16];
    }
  }
}

// ---------------- Kernel C: argmin (exact fp32 rescore) + z_q + loss partial ----------------
__global__ __launch_bounds__(256) void select_kernel(
    const float* __restrict__ ze, const float* __restrict__ cb,
    const float* __restrict__ sim, const float* __restrict__ sqz,
    const float* __restrict__ nse, const float* __restrict__ sqe,
    float* __restrict__ zq, float* __restrict__ ids, float* __restrict__ partials)
{
  __shared__ float s_nse[KCODES];
  __shared__ float s_sqe[KCODES];
  __shared__ float s_part[4];
  const int t = threadIdx.x;
  ((float4*)s_nse)[t] = ((const float4*)nse)[t];
  ((float4*)s_sqe)[t] = ((const float4*)sqe)[t];
  __syncthreads();

  const int lane = t & 63;
  const int row  = blockIdx.x * 4 + (t >> 6);        // wave per row
  const float4 zr = ((const float4*)ze)[(size_t)row * 64 + lane];
  const float  c2 = 2.0f * sqz[row];
  const float4* simr = (const float4*)(sim + (size_t)row * KCODES);

  // dist(row,k) - nsz  (nsz is per-row constant: irrelevant for argmin)
  float v[16];
  float vmin = INFINITY;
#pragma unroll
  for (int i = 0; i < 4; ++i) {
    const float4 s4 = simr[i * 64 + lane];
    const float sv[4] = {s4.x, s4.y, s4.z, s4.w};
#pragma unroll
    for (int c = 0; c < 4; ++c) {
      const int k = i * 256 + lane * 4 + c;
      const float val = s_nse[k] - c2 * s_sqe[k] * sv[c];
      v[i * 4 + c] = val;
      vmin = fminf(vmin, val);
    }
  }
  vmin = wave_min(vmin);
  const float lim = vmin + 1.0f;   // margin ~19 sigma of bf16-dot error

  float tbest = INFINITY; int kbest = KCODES;
#pragma unroll
  for (int idx = 0; idx < 16; ++idx) {
    unsigned long long m = __ballot(v[idx] <= lim);
    const int i = idx >> 2, c = idx & 3;
    while (m) {                                      // uniform across wave
      const int lb = __ffsll(m) - 1;
      m &= m - 1;
      const int kc = i * 256 + lb * 4 + c;
      const float4 er = ((const float4*)cb)[(size_t)kc * 64 + lane];
      float p = wave_sum(zr.x*er.x + zr.y*er.y + zr.z*er.z + zr.w*er.w);
      const float tv = s_nse[kc] - 2.0f * p;         // exact-fp32 dist - nsz
      if (tv < tbest || (tv == tbest && kc < kbest)) { tbest = tv; kbest = kc; }
    }
  }

  const float4 er = ((const float4*)cb)[(size_t)kbest * 64 + lane];
  ((float4*)zq)[(size_t)row * 64 + lane] = er;
  const float dx = zr.x - er.x, dy = zr.y - er.y, dz = zr.z - er.z, dw = zr.w - er.w;
  const float ss = wave_sum(dx*dx + dy*dy + dz*dz + dw*dw);
  if (lane == 0) {
    ids[row] = (float)kbest;
    s_part[t >> 6] = sqrtf(ss);
  }
  __syncthreads();
  if (t == 0)
    partials[blockIdx.x] = (s_part[0] + s_part[1]) + (s_part[2] + s_part[3]);
}

// ---------------- Kernel D: finalize loss (deterministic tree sum) ----------------
__global__ __launch_bounds__(256) void finalize_kernel(
    const float* __restrict__ partials, float* __restrict__ out_loss)
{
  __shared__ float s[4];
  const int t = threadIdx.x;
  float p = 0.0f;
#pragma unroll
  for (int i = 0; i < 32; ++i) p += partials[t + i * 256];  // fixed order
  p = wave_sum(p);
  if ((t & 63) == 0) s[t >> 6] = p;
  __syncthreads();
  if (t == 0) out_loss[0] = 1.25f * ((s[0] + s[1]) + (s[2] + s[3])) / 32768.0f;
}

extern "C" void kernel_launch(void* const* d_in, const int* in_sizes, int n_in,
                              void* d_out, int out_size, void* d_ws, size_t ws_size,
                              hipStream_t stream) {
  const float* ze = (const float*)d_in[0];
  const float* cb = (const float*)d_in[1];

  float* out  = (float*)d_out;
  float* zq   = out;                    // 8388608
  float* sim  = out + 8388608;          // 33554432
  float* ids  = out + 41943040;         // 32768
  float* lout = out + 41975808;         // 1

  char* w = (char*)d_ws;                // ~800 KB of ws used (same footprint as round 1)
  unsigned short* cbb = (unsigned short*)w;           // 1024*256 bf16 = 512 KB
  float* sqz  = (float*)(w + 524288);   // 32768 f32
  float* rsqz = (float*)(w + 655360);   // 32768 f32 (only gemm reads it ->
                                        //  reused as loss partials by select/finalize)
  float* nse  = (float*)(w + 786432);   // 1024 f32
  float* sqe  = (float*)(w + 790528);   // 1024 f32
  float* rsqe = (float*)(w + 794624);   // 1024 f32
  float* partials = rsqz;               // 8192 f32, alias (lifetime-disjoint)

  // bf16 z_e parked in the z_q output slot (16.8 MB < 33.5 MB); select_kernel
  // never reads it and overwrites the slot with the real z_q afterwards.
  unsigned short* zb = (unsigned short*)d_out;

  prep_kernel<<<8448, 256, 0, stream>>>(ze, cb, zb, cbb, sqz, rsqz, nse, sqe, rsqe);
  gemm_sim_kernel<<<2048, 256, 0, stream>>>(zb, cbb, rsqz, rsqe, sim);
  select_kernel<<<8192, 256, 0, stream>>>(ze, cb, sim, sqz, nse, sqe, zq, ids, partials);
  finalize_kernel<<<1, 256, 0, stream>>>(partials, lout);
}

// Round 3
// 72.850 us; speedup vs baseline: 6.4474x; 1.0748x over previous
//
#include <hip/hip_runtime.h>

// VectorQuantiser on MI355X.
// Inputs:  d_in[0] = z_e fp32 (16*2048*256), d_in[1] = codebook fp32 (1024*256)
// Outputs (flat fp32): z_q [8388608] | similarity [33554432] | ids [32768] | loss [1]
//
//   A prep:     z_e,codebook -> bf16 (z bf16 parked in z_q slot); norms.
//   B gemm_sim: bf16 MFMA 128x128 GEMM; epilogue writes sim AND per-row top-2
//               candidate encodings per 64-col strip (enc = qdist*1024+col, 4 MB ws).
//   C select:   per row (1 wave): read 32 encs (128 B), min; if a single candidate
//               within margin -> done; else fp32-exact rescore of candidates.
//               Writes ids, z_q, per-block loss partial (no global atomics).
//   D finalize: deterministic tree-sum; loss = 1.25 * sum / 32768.

#define M_ROWS 32768
#define KCODES 1024
#define DDIM   256
#define ENC_BIG 33554432.0f

typedef __bf16 bf16_t;
typedef __attribute__((ext_vector_type(8))) bf16_t bf16x8;
typedef __attribute__((ext_vector_type(4))) float f32x4;

__device__ __forceinline__ unsigned short f2bf(float f) {
  unsigned u = __float_as_uint(f);
  u += 0x7FFFu + ((u >> 16) & 1u);
  return (unsigned short)(u >> 16);
}

__device__ __forceinline__ float wave_sum(float p) {
#pragma unroll
  for (int o = 1; o < 64; o <<= 1) p += __shfl_xor(p, o);
  return p;
}
__device__ __forceinline__ float wave_min(float p) {
#pragma unroll
  for (int o = 1; o < 64; o <<= 1) p = fminf(p, __shfl_xor(p, o));
  return p;
}

// ---------------- Kernel A: convert + norms ----------------
__global__ __launch_bounds__(256) void prep_kernel(
    const float* __restrict__ ze, const float* __restrict__ cb,
    unsigned short* __restrict__ zb, unsigned short* __restrict__ cbb,
    float* __restrict__ sqz, float* __restrict__ rsqz,
    float* __restrict__ nse, float* __restrict__ sqe, float* __restrict__ rsqe)
{
  const int t = threadIdx.x;
  const int lane = t & 63;
  const int row = blockIdx.x * 4 + (t >> 6);
  if (row < M_ROWS) {
    const float4 z = ((const float4*)ze)[(size_t)row * 64 + lane];
    ushort4 u;
    u.x = f2bf(z.x); u.y = f2bf(z.y); u.z = f2bf(z.z); u.w = f2bf(z.w);
    ((ushort4*)zb)[(size_t)row * 64 + lane] = u;
    float p = wave_sum(z.x*z.x + z.y*z.y + z.z*z.z + z.w*z.w);
    if (lane == 0) { float s = sqrtf(p); sqz[row] = s; rsqz[row] = 1.0f / s; }
  } else {
    const int r = row - M_ROWS;
    const float4 e = ((const float4*)cb)[(size_t)r * 64 + lane];
    ushort4 u;
    u.x = f2bf(e.x); u.y = f2bf(e.y); u.z = f2bf(e.z); u.w = f2bf(e.w);
    ((ushort4*)cbb)[(size_t)r * 64 + lane] = u;
    float p = wave_sum(e.x*e.x + e.y*e.y + e.z*e.z + e.w*e.w);
    if (lane == 0) { nse[r] = p; float s = sqrtf(p); sqe[r] = s; rsqe[r] = 1.0f / s; }
  }
}

// ---------------- Kernel B: bf16 MFMA GEMM + sim + candidate epilogue ----------------
__global__ __launch_bounds__(256, 2) void gemm_sim_kernel(
    const unsigned short* __restrict__ zb, const unsigned short* __restrict__ cbb,
    const float* __restrict__ rsqz, const float* __restrict__ rsqe,
    const float* __restrict__ nse,
    float* __restrict__ sim, float* __restrict__ cand)
{
  __shared__ __attribute__((aligned(128))) unsigned short lds[16384];
  const int tid  = threadIdx.x;
  const int wv   = tid >> 6, lane = tid & 63;
  const int bid  = blockIdx.x;
  const int swz  = (bid & 7) * 256 + (bid >> 3);     // XCD swizzle, nwg=2048 % 8 == 0
  const long row0 = (long)(swz >> 3) * 128;
  const int  col0 = (swz & 7) * 128;

  f32x4 acc[4][4] = {};

  const int rr = lane >> 3, qq = lane & 7;
  const int sq = ((qq ^ rr) << 3);                   // pre-swizzled source quad

  for (int kt = 0; kt < 4; ++kt) {
    const int k0 = kt * 64;
#pragma unroll
    for (int i = 0; i < 4; ++i) {
      const int rbase = wv * 32 + i * 8;
      const unsigned short* srca = zb  + ((size_t)(row0 + rbase + rr)) * DDIM + k0 + sq;
      const unsigned short* srcb = cbb + ((size_t)(col0 + rbase + rr)) * DDIM + k0 + sq;
      __builtin_amdgcn_global_load_lds((const __attribute__((address_space(1))) void*)srca,
                                       (__attribute__((address_space(3))) void*)&lds[rbase * 64],
                                       16, 0, 0);
      __builtin_amdgcn_global_load_lds((const __attribute__((address_space(1))) void*)srcb,
                                       (__attribute__((address_space(3))) void*)&lds[8192 + rbase * 64],
                                       16, 0, 0);
    }
    __syncthreads();
    const int r16 = lane & 15, g = lane >> 4;
#pragma unroll
    for (int ks = 0; ks < 2; ++ks) {
      bf16x8 af[4], bfr[4];
#pragma unroll
      for (int mi = 0; mi < 4; ++mi) {
        const int r  = (wv >> 1) * 64 + mi * 16 + r16;
        const int qy = ((ks * 4 + g) ^ (r & 7)) << 4;
        af[mi] = *(const bf16x8*)((const char*)lds + r * 128 + qy);
      }
#pragma unroll
      for (int ni = 0; ni < 4; ++ni) {
        const int r  = (wv & 1) * 64 + ni * 16 + r16;
        const int qy = ((ks * 4 + g) ^ (r & 7)) << 4;
        bfr[ni] = *(const bf16x8*)((const char*)lds + 16384 + r * 128 + qy);
      }
#pragma unroll
      for (int mi = 0; mi < 4; ++mi)
#pragma unroll
        for (int ni = 0; ni < 4; ++ni)
          acc[mi][ni] = __builtin_amdgcn_mfma_f32_16x16x32_bf16(af[mi], bfr[ni], acc[mi][ni], 0, 0, 0);
    }
    __syncthreads();
  }

  const int r16 = lane & 15, g = lane >> 4;
  const int wm = wv >> 1, wn = wv & 1;

  // sim = dot * rsqz[row] * rsqe[col].  C/D: col = lane&15, row = (lane>>4)*4 + j.
#pragma unroll
  for (int mi = 0; mi < 4; ++mi) {
#pragma unroll
    for (int j = 0; j < 4; ++j) {
      const long row = row0 + wm * 64 + mi * 16 + g * 4 + j;
      const float rz = rsqz[row];
      float* so = sim + (size_t)row * KCODES + col0 + wn * 64 + r16;
#pragma unroll
      for (int ni = 0; ni < 4; ++ni)
        so[ni * 16] = acc[mi][ni][j] * rz * rsqe[col0 + wn * 64 + ni * 16 + r16];
    }
  }

  // Candidate top-2 per (row, 64-col strip). enc = floor((v+1024)*8)*1024 + col (exact int <= 2^24).
  if (cand) {
    float nsev[4];
#pragma unroll
    for (int ni = 0; ni < 4; ++ni) nsev[ni] = nse[col0 + wn * 64 + ni * 16 + r16];
    const int tileIdx = ((col0 >> 6) | wn);          // col0>>6 is even; +wn in {0,1}
#pragma unroll
    for (int mi = 0; mi < 4; ++mi) {
#pragma unroll
      for (int j = 0; j < 4; ++j) {
        float e1 = ENC_BIG, e2 = ENC_BIG;
#pragma unroll
        for (int ni = 0; ni < 4; ++ni) {
          const float v = nsev[ni] - 2.0f * acc[mi][ni][j];
          const float kf = (float)(col0 + wn * 64 + ni * 16 + r16);
          const float enc = floorf((v + 1024.0f) * 8.0f) * 1024.0f + kf;
          if (enc < e1) { e2 = e1; e1 = enc; } else e2 = fminf(e2, enc);
        }
#pragma unroll
        for (int m = 1; m < 16; m <<= 1) {           // reduce across the 16-lane group
          const float p1 = __shfl_xor(e1, m);
          const float p2 = __shfl_xor(e2, m);
          const float n1 = fminf(e1, p1);
          const float n2 = fminf(fmaxf(e1, p1), fminf(e2, p2));
          e1 = n1; e2 = n2;
        }
        if (r16 == 0) {
          const long row = row0 + wm * 64 + mi * 16 + g * 4 + j;
          ((float2*)cand)[row * 16 + tileIdx] = make_float2(e1, e2);
        }
      }
    }
  }
}

// ---------------- Kernel C (fast): candidate-based argmin + z_q + loss ----------------
__global__ __launch_bounds__(256) void select_fast_kernel(
    const float* __restrict__ ze, const float* __restrict__ cb,
    const float* __restrict__ cand, const float* __restrict__ nse,
    float* __restrict__ zq, float* __restrict__ ids, float* __restrict__ partials)
{
  __shared__ float s_part[4];
  const int t = threadIdx.x;
  const int lane = t & 63;
  const int row  = blockIdx.x * 4 + (t >> 6);

  const float4 zr = ((const float4*)ze)[(size_t)row * 64 + lane];

  const float* crow = cand + (size_t)row * 32;
  float e = (lane < 32) ? crow[lane] : ENC_BIG;
  const float m_enc = wave_min(e);
  const float qmin  = floorf(m_enc * 0.0009765625f);   // exact /1024
  const float ql    = floorf(e * 0.0009765625f);

  unsigned long long msk = __ballot(ql <= qmin + 16.0f);  // margin ~2.0 in dist units
  int kbest;
  if (__popcll(msk) == 1) {
    kbest = ((int)m_enc) & 1023;                     // single candidate == the min
  } else {
    float tbest = INFINITY; kbest = KCODES;
    while (msk) {                                    // uniform across wave
      const int lb = __ffsll(msk) - 1;
      msk &= msk - 1;
      const int kc = ((int)__shfl(e, lb)) & 1023;
      const float4 er = ((const float4*)cb)[(size_t)kc * 64 + lane];
      const float p = wave_sum(zr.x*er.x + zr.y*er.y + zr.z*er.z + zr.w*er.w);
      const float tv = nse[kc] - 2.0f * p;           // exact fp32 dist - nsz
      if (tv < tbest || (tv == tbest && kc < kbest)) { tbest = tv; kbest = kc; }
    }
  }

  const float4 er = ((const float4*)cb)[(size_t)kbest * 64 + lane];
  ((float4*)zq)[(size_t)row * 64 + lane] = er;
  const float dx = zr.x - er.x, dy = zr.y - er.y, dz = zr.z - er.z, dw = zr.w - er.w;
  const float ss = wave_sum(dx*dx + dy*dy + dz*dz + dw*dw);
  if (lane == 0) {
    ids[row] = (float)kbest;
    s_part[t >> 6] = sqrtf(ss);
  }
  __syncthreads();
  if (t == 0)
    partials[blockIdx.x] = (s_part[0] + s_part[1]) + (s_part[2] + s_part[3]);
}

// ---------------- Kernel C (fallback, round-2): full sim rescan ----------------
__global__ __launch_bounds__(256) void select_full_kernel(
    const float* __restrict__ ze, const float* __restrict__ cb,
    const float* __restrict__ sim, const float* __restrict__ sqz,
    const float* __restrict__ nse, const float* __restrict__ sqe,
    float* __restrict__ zq, float* __restrict__ ids, float* __restrict__ partials)
{
  __shared__ float s_nse[KCODES];
  __shared__ float s_sqe[KCODES];
  __shared__ float s_part[4];
  const int t = threadIdx.x;
  ((float4*)s_nse)[t] = ((const float4*)nse)[t];
  ((float4*)s_sqe)[t] = ((const float4*)sqe)[t];
  __syncthreads();

  const int lane = t & 63;
  const int row  = blockIdx.x * 4 + (t >> 6);
  const float4 zr = ((const float4*)ze)[(size_t)row * 64 + lane];
  const float  c2 = 2.0f * sqz[row];
  const float4* simr = (const float4*)(sim + (size_t)row * KCODES);

  float v[16];
  float vmin = INFINITY;
#pragma unroll
  for (int i = 0; i < 4; ++i) {
    const float4 s4 = simr[i * 64 + lane];
    const float sv[4] = {s4.x, s4.y, s4.z, s4.w};
#pragma unroll
    for (int c = 0; c < 4; ++c) {
      const int k = i * 256 + lane * 4 + c;
      const float val = s_nse[k] - c2 * s_sqe[k] * sv[c];
      v[i * 4 + c] = val;
      vmin = fminf(vmin, val);
    }
  }
  vmin = wave_min(vmin);
  const float lim = vmin + 1.0f;

  float tbest = INFINITY; int kbest = KCODES;
#pragma unroll
  for (int idx = 0; idx < 16; ++idx) {
    unsigned long long m = __ballot(v[idx] <= lim);
    const int i = idx >> 2, c = idx & 3;
    while (m) {
      const int lb = __ffsll(m) - 1;
      m &= m - 1;
      const int kc = i * 256 + lb * 4 + c;
      const float4 er = ((const float4*)cb)[(size_t)kc * 64 + lane];
      float p = wave_sum(zr.x*er.x + zr.y*er.y + zr.z*er.z + zr.w*er.w);
      const float tv = s_nse[kc] - 2.0f * p;
      if (tv < tbest || (tv == tbest && kc < kbest)) { tbest = tv; kbest = kc; }
    }
  }

  const float4 er = ((const float4*)cb)[(size_t)kbest * 64 + lane];
  ((float4*)zq)[(size_t)row * 64 + lane] = er;
  const float dx = zr.x - er.x, dy = zr.y - er.y, dz = zr.z - er.z, dw = zr.w - er.w;
  const float ss = wave_sum(dx*dx + dy*dy + dz*dz + dw*dw);
  if (lane == 0) {
    ids[row] = (float)kbest;
    s_part[t >> 6] = sqrtf(ss);
  }
  __syncthreads();
  if (t == 0)
    partials[blockIdx.x] = (s_part[0] + s_part[1]) + (s_part[2] + s_part[3]);
}

// ---------------- Kernel D: finalize loss ----------------
__global__ __launch_bounds__(256) void finalize_kernel(
    const float* __restrict__ partials, float* __restrict__ out_loss)
{
  __shared__ float s[4];
  const int t = threadIdx.x;
  float p = 0.0f;
#pragma unroll
  for (int i = 0; i < 32; ++i) p += partials[t + i * 256];
  p = wave_sum(p);
  if ((t & 63) == 0) s[t >> 6] = p;
  __syncthreads();
  if (t == 0) out_loss[0] = 1.25f * ((s[0] + s[1]) + (s[2] + s[3])) / 32768.0f;
}

extern "C" void kernel_launch(void* const* d_in, const int* in_sizes, int n_in,
                              void* d_out, int out_size, void* d_ws, size_t ws_size,
                              hipStream_t stream) {
  const float* ze = (const float*)d_in[0];
  const float* cb = (const float*)d_in[1];

  float* out  = (float*)d_out;
  float* zq   = out;                    // 8388608
  float* sim  = out + 8388608;          // 33554432
  float* ids  = out + 41943040;         // 32768
  float* lout = out + 41975808;         // 1

  char* w = (char*)d_ws;
  unsigned short* cbb = (unsigned short*)w;           // 512 KB
  float* sqz  = (float*)(w + 524288);   // 128 KB
  float* rsqz = (float*)(w + 655360);   // 128 KB (reused as loss partials later)
  float* nse  = (float*)(w + 786432);   // 4 KB
  float* sqe  = (float*)(w + 790528);   // 4 KB
  float* rsqe = (float*)(w + 794624);   // 4 KB
  float* cand = (float*)(w + 798720);   // 4 MB (32768*16 float2)
  float* partials = rsqz;               // lifetime-disjoint alias

  const bool fast = ws_size >= (size_t)(798720 + 4 * 1024 * 1024 + 256);

  // bf16 z_e parked in the z_q output slot; overwritten by select at the end.
  unsigned short* zb = (unsigned short*)d_out;

  prep_kernel<<<8448, 256, 0, stream>>>(ze, cb, zb, cbb, sqz, rsqz, nse, sqe, rsqe);
  gemm_sim_kernel<<<2048, 256, 0, stream>>>(zb, cbb, rsqz, rsqe, nse, sim,
                                            fast ? cand : nullptr);
  if (fast)
    select_fast_kernel<<<8192, 256, 0, stream>>>(ze, cb, cand, nse, zq, ids, partials);
  else
    select_full_kernel<<<8192, 256, 0, stream>>>(ze, cb, sim, sqz, nse, sqe, zq, ids, partials);
  finalize_kernel<<<1, 256, 0, stream>>>(partials, lout);
}